// Round 10
// baseline (267.469 us; speedup 1.0000x reference)
//
#include <hip/hip_runtime.h>
#include <math.h>

#define DD    256
#define PLQ   65536           // plane elems (u16) = 256*256
#define SLOTB 131072          // complex slot elems (u16): re plane + im plane
#define NTS   128
#define DT_C  0.02f

typedef unsigned short u16;
typedef unsigned int   u32;
typedef __attribute__((ext_vector_type(8))) short s16x8;
typedef __attribute__((ext_vector_type(4))) float f32x4;

typedef __attribute__((address_space(1))) const unsigned int GU32;
typedef __attribute__((address_space(3))) unsigned int LU32;

// Plane = [64 rows][128B = 64 k-elems x 2B], XOR-swizzled. Involution.
__device__ __forceinline__ u32 swzB(u32 b) {
    return b ^ (((((b >> 7) ^ (b >> 10)) & 7u)) << 4);
}
__device__ __forceinline__ u16 f2bf(float f) {
    u32 u = __float_as_uint(f);
    return (u16)((u + 0x7FFFu + ((u >> 16) & 1u)) >> 16);
}
__device__ __forceinline__ float bf2f(u16 h) {
    return __uint_as_float(((u32)h) << 16);
}
__device__ __forceinline__ void gll16(const u16* g, char* ldsBase, u32 ldsByteOff) {
    u32 off = (u32)__builtin_amdgcn_readfirstlane((int)ldsByteOff);
    __builtin_amdgcn_global_load_lds((GU32*)g, (LU32*)(ldsBase + off), 16, 0, 0);
}

// ---------------------------------------------------------------------------
// build: X = DT * A_ts (bf16), written in BOTH N and T layouts (LDS transpose).
// ---------------------------------------------------------------------------
__global__ __launch_bounds__(256)
void build_kernel(const float* __restrict__ cr, const float* __restrict__ ci,
                  const float* __restrict__ dre, const float* __restrict__ dimg,
                  const float* __restrict__ gre, const float* __restrict__ gim,
                  u16* __restrict__ Xn, u16* __restrict__ Xt, int ts0)
{
    __shared__ u16 tre[64][66], tim[64][66];

    const int ts = blockIdx.y;
    const int k  = ts0 + ts;
    const int bx = blockIdx.x;                 // 0..15
    const int r0 = (bx >> 2) * 64, c0 = (bx & 3) * 64;
    const int t  = threadIdx.x;
    const int tr = t >> 4;                     // 0..15
    const int tc = (t & 15) * 4;               // 0..60

    const float c0f = cr[2*k], c1f = cr[2*k+1];
    const float e0f = ci[2*k], e1f = ci[2*k+1];

    u16* XN = Xn + (size_t)ts * SLOTB;
    u16* XT = Xt + (size_t)ts * SLOTB;

    #pragma unroll
    for (int g = 0; g < 4; ++g) {
        const int lr  = g*16 + tr;
        const int idx = (r0 + lr)*DD + (c0 + tc);
        const float4 g0r = *(const float4*)&gre[0*PLQ + idx];
        const float4 g1r = *(const float4*)&gre[1*PLQ + idx];
        const float4 g2r = *(const float4*)&gre[2*PLQ + idx];
        const float4 g3r = *(const float4*)&gre[3*PLQ + idx];
        const float4 g0i = *(const float4*)&gim[0*PLQ + idx];
        const float4 g1i = *(const float4*)&gim[1*PLQ + idx];
        const float4 g2i = *(const float4*)&gim[2*PLQ + idx];
        const float4 g3i = *(const float4*)&gim[3*PLQ + idx];
        const float4 d_r = *(const float4*)&dre[idx];
        const float4 d_i = *(const float4*)&dimg[idx];
        const float* gr00 = &g0r.x; const float* gr01 = &g1r.x;
        const float* gr10 = &g2r.x; const float* gr11 = &g3r.x;
        const float* gi00 = &g0i.x; const float* gi01 = &g1i.x;
        const float* gi10 = &g2i.x; const float* gi11 = &g3i.x;
        const float* dr4  = &d_r.x; const float* di4  = &d_i.x;
        ushort4 hr, hi;
        u16* hrp = &hr.x; u16* hip = &hi.x;
        #pragma unroll
        for (int j = 0; j < 4; ++j) {
            const float are = dr4[j] + c0f*(gr00[j]+gr01[j]) + c1f*(gr10[j]+gr11[j])
                                     - e0f*(gi00[j]-gi01[j]) - e1f*(gi10[j]-gi11[j]);
            const float aim = di4[j] + c0f*(gi00[j]+gi01[j]) + c1f*(gi10[j]+gi11[j])
                                     + e0f*(gr00[j]-gr01[j]) + e1f*(gr10[j]-gr11[j]);
            hrp[j] = f2bf(DT_C * are);
            hip[j] = f2bf(DT_C * aim);
            tre[lr][tc + j] = hrp[j];
            tim[lr][tc + j] = hip[j];
        }
        *(ushort4*)&XN[idx]       = hr;
        *(ushort4*)&XN[PLQ + idx] = hi;
    }
    __syncthreads();
    #pragma unroll
    for (int g = 0; g < 4; ++g) {
        const int trow = g*16 + tr;            // local col of X
        const int oidx = (c0 + trow)*DD + r0 + tc;
        ushort4 hr, hi;
        hr.x = tre[tc+0][trow]; hr.y = tre[tc+1][trow];
        hr.z = tre[tc+2][trow]; hr.w = tre[tc+3][trow];
        hi.x = tim[tc+0][trow]; hi.y = tim[tc+1][trow];
        hi.z = tim[tc+2][trow]; hi.w = tim[tc+3][trow];
        *(ushort4*)&XT[oidx]       = hr;
        *(ushort4*)&XT[PLQ + oidx] = hi;
    }
}

// ---------------------------------------------------------------------------
// FUSED expm: per block, E-tile(bm,bn) = X + P2/2 + (P2@X)/6 with P2 = X@X
// computed in 64x64 k-chunks held in LDS (never in global).
// LDS: staging A re/im @0/8K, staging B re/im @16K/24K, P2 re/im @32K/40K.
// ---------------------------------------------------------------------------
__global__ __launch_bounds__(256)
void expm_fused(const u16* __restrict__ Xnb, const u16* __restrict__ Xtb,
                u16* __restrict__ Eb, int eO)
{
    __shared__ char lds[49152];

    const u32 nwg = 16u * (u32)gridDim.z;
    const u32 wg  = (u32)blockIdx.x + 4u*(u32)blockIdx.y + 16u*(u32)blockIdx.z;
    const u32 q   = nwg >> 3;
    const u32 w   = (wg & 7u) * q + (wg >> 3);
    const int bn = (int)(w & 3u) * 64;
    const int bm = (int)((w >> 2) & 3u) * 64;
    const int z  = (int)(w >> 4);

    const u16* XN = Xnb + (size_t)z * SLOTB;
    const u16* XT = Xtb + (size_t)z * SLOTB;

    const int t = threadIdx.x;
    const u32 b0 = (u32)t * 16u, b1 = 4096u + (u32)t * 16u;
    const u32 L0 = swzB(b0),     L1 = swzB(b1);
    const int r0 = (int)(L0 >> 7), k0 = (int)((L0 & 127u) >> 1);
    const int r1 = (int)(L1 >> 7), k1 = (int)((L1 & 127u) >> 1);
    const u32 wvoff = ((u32)(t >> 6)) * 1024u;

    const int wv = t >> 6, ln = t & 63;
    const int wrow = (wv >> 1) * 32, wcol = (wv & 1) * 32;
    const int lg = ln >> 4, lc = ln & 15;

    f32x4 aER[2][2], aEI[2][2];
    #pragma unroll
    for (int i = 0; i < 2; ++i)
        #pragma unroll
        for (int j = 0; j < 2; ++j) {
            aER[i][j] = (f32x4){0.f,0.f,0.f,0.f};
            aEI[i][j] = (f32x4){0.f,0.f,0.f,0.f};
        }

    for (int kk = 0; kk < 4; ++kk) {
        // ---------------- phase A: P2chunk = X[bm,:] @ X[:,kk*64] ----------
        f32x4 aAR[2][2], aAI[2][2];
        #pragma unroll
        for (int i = 0; i < 2; ++i)
            #pragma unroll
            for (int j = 0; j < 2; ++j) {
                aAR[i][j] = (f32x4){0.f,0.f,0.f,0.f};
                aAI[i][j] = (f32x4){0.f,0.f,0.f,0.f};
            }

        for (int it = 0; it < 4; ++it) {
            __syncthreads();               // staging buffers free
            const int kb = it*64;
            gll16(XN +       (size_t)(bm + r0)*DD + kb + k0, lds, wvoff +     0u);
            gll16(XN +       (size_t)(bm + r1)*DD + kb + k1, lds, wvoff +  4096u);
            gll16(XN + PLQ + (size_t)(bm + r0)*DD + kb + k0, lds, wvoff +  8192u);
            gll16(XN + PLQ + (size_t)(bm + r1)*DD + kb + k1, lds, wvoff + 12288u);
            gll16(XT +       (size_t)(kk*64 + r0)*DD + kb + k0, lds, wvoff + 16384u);
            gll16(XT +       (size_t)(kk*64 + r1)*DD + kb + k1, lds, wvoff + 20480u);
            gll16(XT + PLQ + (size_t)(kk*64 + r0)*DD + kb + k0, lds, wvoff + 24576u);
            gll16(XT + PLQ + (size_t)(kk*64 + r1)*DD + kb + k1, lds, wvoff + 28672u);
            __syncthreads();               // staged data ready

            #pragma unroll
            for (int s = 0; s < 2; ++s) {
                s16x8 ar[2], ai[2], br[2], bi[2];
                #pragma unroll
                for (int fm = 0; fm < 2; ++fm) {
                    const u32 so = swzB((u32)(wrow + fm*16 + lc)*128u + (u32)(s*4 + lg)*16u);
                    ar[fm] = *(const s16x8*)(lds + so);
                    ai[fm] = *(const s16x8*)(lds + 8192 + so);
                }
                #pragma unroll
                for (int fn = 0; fn < 2; ++fn) {
                    const u32 so = swzB((u32)(wcol + fn*16 + lc)*128u + (u32)(s*4 + lg)*16u);
                    br[fn] = *(const s16x8*)(lds + 16384 + so);
                    bi[fn] = *(const s16x8*)(lds + 24576 + so);
                }
                #pragma unroll
                for (int fm = 0; fm < 2; ++fm)
                    #pragma unroll
                    for (int fn = 0; fn < 2; ++fn) {
                        aAI[fm][fn] = __builtin_amdgcn_mfma_f32_16x16x32_bf16(ar[fm], bi[fn], aAI[fm][fn], 0, 0, 0);
                        aAI[fm][fn] = __builtin_amdgcn_mfma_f32_16x16x32_bf16(ai[fm], br[fn], aAI[fm][fn], 0, 0, 0);
                    }
                #pragma unroll
                for (int fm = 0; fm < 2; ++fm) ai[fm] ^= (short)0x8000u;
                #pragma unroll
                for (int fm = 0; fm < 2; ++fm)
                    #pragma unroll
                    for (int fn = 0; fn < 2; ++fn) {
                        aAR[fm][fn] = __builtin_amdgcn_mfma_f32_16x16x32_bf16(ar[fm], br[fn], aAR[fm][fn], 0, 0, 0);
                        aAR[fm][fn] = __builtin_amdgcn_mfma_f32_16x16x32_bf16(ai[fm], bi[fn], aAR[fm][fn], 0, 0, 0);
                    }
            }
        }

        // write P2chunk (bf16) to LDS @32K/40K; fold 3*P2 into E-acc if own chunk
        const int own = (kk == (bn >> 6));
        #pragma unroll
        for (int fm = 0; fm < 2; ++fm)
            #pragma unroll
            for (int fn = 0; fn < 2; ++fn) {
                #pragma unroll
                for (int j = 0; j < 4; ++j) {
                    const int r  = wrow + fm*16 + lg*4 + j;
                    const int c  = wcol + fn*16 + lc;
                    const u32 ob = swzB((u32)r*128u + (u32)c*2u);
                    *(u16*)(lds + 32768 + ob) = f2bf(aAR[fm][fn][j]);
                    *(u16*)(lds + 40960 + ob) = f2bf(aAI[fm][fn][j]);
                }
                if (own) {
                    aER[fm][fn] += 3.0f * aAR[fm][fn];
                    aEI[fm][fn] += 3.0f * aAI[fm][fn];
                }
            }
        __syncthreads();                   // P2 ready; staging free

        // ---------------- phase B: aE += P2chunk @ X[kk*64, bn] ------------
        {
            gll16(XT +       (size_t)(bn + r0)*DD + kk*64 + k0, lds, wvoff + 16384u);
            gll16(XT +       (size_t)(bn + r1)*DD + kk*64 + k1, lds, wvoff + 20480u);
            gll16(XT + PLQ + (size_t)(bn + r0)*DD + kk*64 + k0, lds, wvoff + 24576u);
            gll16(XT + PLQ + (size_t)(bn + r1)*DD + kk*64 + k1, lds, wvoff + 28672u);
        }
        __syncthreads();

        #pragma unroll
        for (int s = 0; s < 2; ++s) {
            s16x8 ar[2], ai[2], br[2], bi[2];
            #pragma unroll
            for (int fm = 0; fm < 2; ++fm) {
                const u32 so = swzB((u32)(wrow + fm*16 + lc)*128u + (u32)(s*4 + lg)*16u);
                ar[fm] = *(const s16x8*)(lds + 32768 + so);
                ai[fm] = *(const s16x8*)(lds + 40960 + so);
            }
            #pragma unroll
            for (int fn = 0; fn < 2; ++fn) {
                const u32 so = swzB((u32)(wcol + fn*16 + lc)*128u + (u32)(s*4 + lg)*16u);
                br[fn] = *(const s16x8*)(lds + 16384 + so);
                bi[fn] = *(const s16x8*)(lds + 24576 + so);
            }
            #pragma unroll
            for (int fm = 0; fm < 2; ++fm)
                #pragma unroll
                for (int fn = 0; fn < 2; ++fn) {
                    aEI[fm][fn] = __builtin_amdgcn_mfma_f32_16x16x32_bf16(ar[fm], bi[fn], aEI[fm][fn], 0, 0, 0);
                    aEI[fm][fn] = __builtin_amdgcn_mfma_f32_16x16x32_bf16(ai[fm], br[fn], aEI[fm][fn], 0, 0, 0);
                }
            #pragma unroll
            for (int fm = 0; fm < 2; ++fm) ai[fm] ^= (short)0x8000u;
            #pragma unroll
            for (int fm = 0; fm < 2; ++fm)
                #pragma unroll
                for (int fn = 0; fn < 2; ++fn) {
                    aER[fm][fn] = __builtin_amdgcn_mfma_f32_16x16x32_bf16(ar[fm], br[fn], aER[fm][fn], 0, 0, 0);
                    aER[fm][fn] = __builtin_amdgcn_mfma_f32_16x16x32_bf16(ai[fm], bi[fn], aER[fm][fn], 0, 0, 0);
                }
        }
        __syncthreads();                   // phase-B reads done before next kk
    }

    // ---- epilogue: E = aE/6 + X ----
    u16* EO = Eb + (size_t)(z + eO) * SLOTB;
    const float s6 = 1.0f / 6.0f;
    #pragma unroll
    for (int fm = 0; fm < 2; ++fm)
        #pragma unroll
        for (int fn = 0; fn < 2; ++fn) {
            const int rb = bm + wrow + fm*16 + lg*4;
            const int c  = bn + wcol + fn*16 + lc;
            #pragma unroll
            for (int j = 0; j < 4; ++j) {
                const int r = rb + j;
                const float xr = bf2f(XN[(size_t)r*DD + c]);
                const float xi = bf2f(XN[PLQ + (size_t)r*DD + c]);
                EO[(size_t)r*DD + c]       = f2bf(s6*aER[fm][fn][j] + xr);
                EO[PLQ + (size_t)r*DD + c] = f2bf(s6*aEI[fm][fn][j] + xi);
            }
        }
}

// ---------------------------------------------------------------------------
// Batched complex bf16 MFMA GEMM (round-9 proven), for the product tree.
// ---------------------------------------------------------------------------
template<int TRB>
__global__ __launch_bounds__(256)
void cgemm(const u16* __restrict__ Ab, const u16* __restrict__ Bb,
           u16* __restrict__ outN, u16* __restrict__ outT,
           const u16* __restrict__ X1b, const u16* __restrict__ X2b,
           float aN, float bN1, float bN2,
           float aT, float bT1, float bT2,
           int aS, int aO, int bS, int bO, int cS, int cO,
           int x1S, int x1O, int x2S, int x2O)
{
    __shared__ char lds[32768];

    const u32 nwg = 16u * (u32)gridDim.z;
    const u32 wg  = (u32)blockIdx.x + 4u*(u32)blockIdx.y + 16u*(u32)blockIdx.z;
    const u32 q   = nwg >> 3;
    const u32 w   = (wg & 7u) * q + (wg >> 3);
    const int bn = (int)(w & 3u) * 64;
    const int bm = (int)((w >> 2) & 3u) * 64;
    const int z  = (int)(w >> 4);

    const u16* __restrict__ A = Ab + (size_t)(z*aS + aO) * SLOTB;
    const u16* __restrict__ B = Bb + (size_t)(z*bS + bO) * SLOTB;

    const int t = threadIdx.x;

    const u32 b0 = (u32)t * 16u, b1 = 4096u + (u32)t * 16u;
    const u32 L0 = swzB(b0),     L1 = swzB(b1);
    const int rA0 = (int)(L0 >> 7), kA0 = (int)((L0 & 127u) >> 1);
    const int rA1 = (int)(L1 >> 7), kA1 = (int)((L1 & 127u) >> 1);
    const u32 wvoff = ((u32)(t >> 6)) * 1024u;

    const u16* pA0 = A + (size_t)(bm + rA0)*DD + kA0;
    const u16* pA1 = A + (size_t)(bm + rA1)*DD + kA1;
    const u16* pB0 = (TRB == 0) ? (B + (size_t)(bn + rA0)*DD + kA0) : nullptr;
    const u16* pB1 = (TRB == 0) ? (B + (size_t)(bn + rA1)*DD + kA1) : nullptr;

    const int kRow = t >> 3;                   // 0..31
    const int nCh  = t & 7;                    // n0 = nCh*8

    const int wv = t >> 6, ln = t & 63;
    const int wrow = (wv >> 1) * 32, wcol = (wv & 1) * 32;
    const int lg = ln >> 4, lc = ln & 15;

    f32x4 accR[2][2], accI[2][2];
    #pragma unroll
    for (int i = 0; i < 2; ++i)
        #pragma unroll
        for (int j = 0; j < 2; ++j) {
            accR[i][j] = (f32x4){0.f,0.f,0.f,0.f};
            accI[i][j] = (f32x4){0.f,0.f,0.f,0.f};
        }

    {
        gll16(pA0,       lds, wvoff +     0u);
        gll16(pA1,       lds, wvoff +  4096u);
        gll16(pA0 + PLQ, lds, wvoff +  8192u);
        gll16(pA1 + PLQ, lds, wvoff + 12288u);
        if (TRB == 0) {
            gll16(pB0,       lds, wvoff + 16384u);
            gll16(pB1,       lds, wvoff + 20480u);
            gll16(pB0 + PLQ, lds, wvoff + 24576u);
            gll16(pB1 + PLQ, lds, wvoff + 28672u);
        } else {
            #pragma unroll
            for (int h = 0; h < 2; ++h) {
                const int kk = h*32 + kRow;
                const s16x8 vr = *(const s16x8*)(B +       (size_t)kk*DD + bn + nCh*8);
                const s16x8 vi = *(const s16x8*)(B + PLQ + (size_t)kk*DD + bn + nCh*8);
                #pragma unroll
                for (int e = 0; e < 8; ++e) {
                    const u32 off = swzB((u32)(nCh*8 + e)*128u + (u32)kk*2u);
                    *(u16*)(lds + 16384 + off) = (u16)vr[e];
                    *(u16*)(lds + 24576 + off) = (u16)vi[e];
                }
            }
        }
    }
    __syncthreads();

    for (int it = 0; it < 4; ++it) {
        s16x8 nvr0, nvi0, nvr1, nvi1;
        if (TRB == 1 && it < 3) {
            const int k1 = 64*(it + 1);
            nvr0 = *(const s16x8*)(B +       (size_t)(k1 + kRow)*DD + bn + nCh*8);
            nvi0 = *(const s16x8*)(B + PLQ + (size_t)(k1 + kRow)*DD + bn + nCh*8);
            nvr1 = *(const s16x8*)(B +       (size_t)(k1 + 32 + kRow)*DD + bn + nCh*8);
            nvi1 = *(const s16x8*)(B + PLQ + (size_t)(k1 + 32 + kRow)*DD + bn + nCh*8);
        }

        #pragma unroll
        for (int s = 0; s < 2; ++s) {
            s16x8 ar[2], ai[2], br[2], bi[2];
            #pragma unroll
            for (int fm = 0; fm < 2; ++fm) {
                const u32 so = swzB((u32)(wrow + fm*16 + lc)*128u + (u32)(s*4 + lg)*16u);
                ar[fm] = *(const s16x8*)(lds + so);
                ai[fm] = *(const s16x8*)(lds + 8192 + so);
            }
            #pragma unroll
            for (int fn = 0; fn < 2; ++fn) {
                const u32 so = swzB((u32)(wcol + fn*16 + lc)*128u + (u32)(s*4 + lg)*16u);
                br[fn] = *(const s16x8*)(lds + 16384 + so);
                bi[fn] = *(const s16x8*)(lds + 24576 + so);
            }
            #pragma unroll
            for (int fm = 0; fm < 2; ++fm)
                #pragma unroll
                for (int fn = 0; fn < 2; ++fn) {
                    accI[fm][fn] = __builtin_amdgcn_mfma_f32_16x16x32_bf16(ar[fm], bi[fn], accI[fm][fn], 0, 0, 0);
                    accI[fm][fn] = __builtin_amdgcn_mfma_f32_16x16x32_bf16(ai[fm], br[fn], accI[fm][fn], 0, 0, 0);
                }
            #pragma unroll
            for (int fm = 0; fm < 2; ++fm) ai[fm] ^= (short)0x8000u;
            #pragma unroll
            for (int fm = 0; fm < 2; ++fm)
                #pragma unroll
                for (int fn = 0; fn < 2; ++fn) {
                    accR[fm][fn] = __builtin_amdgcn_mfma_f32_16x16x32_bf16(ar[fm], br[fn], accR[fm][fn], 0, 0, 0);
                    accR[fm][fn] = __builtin_amdgcn_mfma_f32_16x16x32_bf16(ai[fm], bi[fn], accR[fm][fn], 0, 0, 0);
                }
        }

        if (it < 3) {
            const int k1 = 64*(it + 1);
            __syncthreads();
            gll16(pA0 + k1,       lds, wvoff +     0u);
            gll16(pA1 + k1,       lds, wvoff +  4096u);
            gll16(pA0 + PLQ + k1, lds, wvoff +  8192u);
            gll16(pA1 + PLQ + k1, lds, wvoff + 12288u);
            if (TRB == 0) {
                gll16(pB0 + k1,       lds, wvoff + 16384u);
                gll16(pB1 + k1,       lds, wvoff + 20480u);
                gll16(pB0 + PLQ + k1, lds, wvoff + 24576u);
                gll16(pB1 + PLQ + k1, lds, wvoff + 28672u);
            } else {
                #pragma unroll
                for (int e = 0; e < 8; ++e) {
                    const u32 off0 = swzB((u32)(nCh*8 + e)*128u + (u32)kRow*2u);
                    const u32 off1 = swzB((u32)(nCh*8 + e)*128u + (u32)(32 + kRow)*2u);
                    *(u16*)(lds + 16384 + off0) = (u16)nvr0[e];
                    *(u16*)(lds + 24576 + off0) = (u16)nvi0[e];
                    *(u16*)(lds + 16384 + off1) = (u16)nvr1[e];
                    *(u16*)(lds + 24576 + off1) = (u16)nvi1[e];
                }
            }
            __syncthreads();
        }
    }

    u16* oN = outN ? outN + (size_t)(z*cS + cO) * SLOTB : nullptr;
    u16* oT = outT ? outT + (size_t)(z*cS + cO) * SLOTB : nullptr;
    const u16* x1 = X1b ? X1b + (size_t)(z*x1S + x1O) * SLOTB : nullptr;
    const u16* x2 = X2b ? X2b + (size_t)(z*x2S + x2O) * SLOTB : nullptr;

    #pragma unroll
    for (int fm = 0; fm < 2; ++fm)
        #pragma unroll
        for (int fn = 0; fn < 2; ++fn) {
            const int rb = bm + wrow + fm*16 + lg*4;
            const int c  = bn + wcol + fn*16 + lc;
            u16 tR[4], tI[4];
            #pragma unroll
            for (int j = 0; j < 4; ++j) {
                const int r = rb + j;
                float x1r = 0.f, x1i = 0.f, x2r = 0.f, x2i = 0.f;
                if (x1) { x1r = bf2f(x1[(size_t)r*DD + c]);
                          x1i = bf2f(x1[PLQ + (size_t)r*DD + c]); }
                if (x2) { x2r = bf2f(x2[(size_t)r*DD + c]);
                          x2i = bf2f(x2[PLQ + (size_t)r*DD + c]); }
                if (oN) {
                    oN[(size_t)r*DD + c]       = f2bf(aN*accR[fm][fn][j] + bN1*x1r + bN2*x2r);
                    oN[PLQ + (size_t)r*DD + c] = f2bf(aN*accI[fm][fn][j] + bN1*x1i + bN2*x2i);
                }
                tR[j] = f2bf(aT*accR[fm][fn][j] + bT1*x1r + bT2*x2r);
                tI[j] = f2bf(aT*accI[fm][fn][j] + bT1*x1i + bT2*x2i);
            }
            if (oT) {
                *(ushort4*)(oT + (size_t)c*DD + rb)       = make_ushort4(tR[0], tR[1], tR[2], tR[3]);
                *(ushort4*)(oT + PLQ + (size_t)c*DD + rb) = make_ushort4(tI[0], tI[1], tI[2], tI[3]);
            }
        }
}

// ---------------------------------------------------------------------------
// final: v = s0 + Etot@s0 ; c = sum(v[diag]) ; sT = v/c ; fid = ||sT-tgt||_F
// ---------------------------------------------------------------------------
__global__ __launch_bounds__(256)
void final_kernel(const u16* __restrict__ Et,
                  const float* __restrict__ s0r, const float* __restrict__ s0i,
                  const float* __restrict__ tgr, const float* __restrict__ tgi,
                  float* __restrict__ out, int outSize)
{
    __shared__ float sr[DD], si[DD], red[DD];
    __shared__ float cR, cI;
    const int t = threadIdx.x;
    sr[t] = s0r[t];
    si[t] = s0i[t];
    __syncthreads();

    const u16* Er = Et + (size_t)t*DD;
    const u16* Ei = Er + PLQ;
    float ar = sr[t], ai = si[t];
    for (int kk = 0; kk < DD/8; ++kk) {
        const s16x8 er = *(const s16x8*)(Er + kk*8);
        const s16x8 ei = *(const s16x8*)(Ei + kk*8);
        #pragma unroll
        for (int jj = 0; jj < 8; ++jj) {
            const float pr = bf2f((u16)er[jj]);
            const float pi = bf2f((u16)ei[jj]);
            const int k = kk*8 + jj;
            ar += pr*sr[k] - pi*si[k];
            ai += pr*si[k] + pi*sr[k];
        }
    }
    __syncthreads();
    sr[t] = ar; si[t] = ai;
    __syncthreads();

    if (t == 0) {
        float xr = 0.f, xi = 0.f;
        for (int i = 0; i < 16; ++i) { xr += sr[i*17]; xi += si[i*17]; }
        cR = xr; cI = xi;
    }
    __syncthreads();

    const float den = cR*cR + cI*cI;
    const float str = (ar*cR + ai*cI) / den;
    const float sti = (ai*cR - ar*cI) / den;

    const float dr = str - tgr[t];
    const float di = sti - tgi[t];
    red[t] = dr*dr + di*di;
    __syncthreads();
    for (int s = 128; s > 0; s >>= 1) {
        if (t < s) red[t] += red[t + s];
        __syncthreads();
    }
    const float fid = sqrtf(red[0]);

    if (outSize >= 2*DD + 1) {
        out[2*t] = str; out[2*t+1] = sti;
        if (t == 0) out[2*DD] = fid;
    } else if (outSize == 2*DD) {
        out[2*t] = str; out[2*t+1] = sti;
    } else {
        out[t] = str;
        if (t == 0 && outSize > DD) out[DD] = fid;
    }
}

// ---------------------------------------------------------------------------
extern "C" void kernel_launch(void* const* d_in, const int* in_sizes, int n_in,
                              void* d_out, int out_size, void* d_ws, size_t ws_size,
                              hipStream_t stream)
{
    (void)in_sizes; (void)n_in;
    const float* cr   = (const float*)d_in[0];
    const float* ci   = (const float*)d_in[1];
    const float* dre  = (const float*)d_in[2];
    const float* dimg = (const float*)d_in[3];
    const float* gre  = (const float*)d_in[4];
    const float* gim  = (const float*)d_in[5];
    const float* s0r  = (const float*)d_in[6];
    const float* s0i  = (const float*)d_in[7];
    const float* tgr  = (const float*)d_in[8];
    const float* tgi  = (const float*)d_in[9];

    u16* ws = (u16*)d_ws;
    const long slots = (long)(ws_size / 2) / SLOTB;

    if (slots >= 384) {
        // ============ FAST PATH: z=128, 3 regions ============
        u16* RX = ws;                      // X-N; later tree ping (N|T)
        u16* XT = ws + 128L * SLOTB;       // X-T
        u16* R1 = ws + 256L * SLOTB;       // E; later tree pong

        build_kernel<<<dim3(16, 128), 256, 0, stream>>>(
            cr, ci, dre, dimg, gre, gim, RX, XT, 0);

        expm_fused<<<dim3(4, 4, 128), 256, 0, stream>>>(RX, XT, R1, 0);

        // ---- tree: E' = Ea@Eb + Ea + Eb; L1 scatter-B, dual N+T out ----
        cgemm<1><<<dim3(4, 4, 64), 256, 0, stream>>>(
            R1, R1, RX, RX + 64L*SLOTB, R1, R1,
            1.f, 1.f, 1.f,  1.f, 1.f, 1.f,
            2,1, 2,0, 1,0, 2,1, 2,0);
        u16* cur = RX;
        u16* oth = R1;
        for (int n = 64; n > 1; n >>= 1) {
            const bool last = (n == 2);
            cgemm<0><<<dim3(4, 4, n/2), 256, 0, stream>>>(
                cur, cur, oth, last ? nullptr : oth + (size_t)(n/2)*SLOTB,
                cur, cur,
                1.f, 1.f, 1.f,  1.f, 1.f, 1.f,
                2,1, 2,(int)n, 1,0, 2,1, 2,0);
            u16* tmp = cur; cur = oth; oth = tmp;
        }
        final_kernel<<<1, 256, 0, stream>>>(cur, s0r, s0i, tgr, tgi,
                                            (float*)d_out, out_size);
    } else {
        // ============ FALLBACK: chunked (P + 2C regions) ====================
        u16* P  = ws;
        u16* CB = ws + 128L * SLOTB;
        int Cmax = (int)((slots - 128) / 2);
        if (Cmax > NTS) Cmax = NTS;
        if (Cmax < 64)  Cmax = 64;         // tree ping needs 2C >= 128
        const int nch = (NTS + Cmax - 1) / Cmax;
        const int C   = (NTS + nch - 1) / nch;

        for (int ts0 = 0; ts0 < NTS; ts0 += C) {
            int nb = NTS - ts0; if (nb > C) nb = C;
            u16* Xn = CB;
            u16* Xt = CB + 1L*C*SLOTB;

            build_kernel<<<dim3(16, nb), 256, 0, stream>>>(
                cr, ci, dre, dimg, gre, gim, Xn, Xt, ts0);
            expm_fused<<<dim3(4, 4, nb), 256, 0, stream>>>(Xn, Xt, P, ts0);
        }

        // tree: L1 dual-out into CB (needs 128 slots), then ping-pong CB<->P
        cgemm<1><<<dim3(4, 4, 64), 256, 0, stream>>>(
            P, P, CB, CB + 64L*SLOTB, P, P,
            1.f, 1.f, 1.f,  1.f, 1.f, 1.f,
            2,1, 2,0, 1,0, 2,1, 2,0);
        u16* cur = CB;
        u16* oth = P;
        for (int n = 64; n > 1; n >>= 1) {
            const bool last = (n == 2);
            cgemm<0><<<dim3(4, 4, n/2), 256, 0, stream>>>(
                cur, cur, oth, last ? nullptr : oth + (size_t)(n/2)*SLOTB,
                cur, cur,
                1.f, 1.f, 1.f,  1.f, 1.f, 1.f,
                2,1, 2,(int)n, 1,0, 2,1, 2,0);
            u16* tmp = cur; cur = oth; oth = tmp;
        }
        final_kernel<<<1, 256, 0, stream>>>(cur, s0r, s0i, tgr, tgi,
                                            (float*)d_out, out_size);
    }
}

// Round 11
// 214.687 us; speedup vs baseline: 1.2459x; 1.2459x over previous
//
#include <hip/hip_runtime.h>
#include <math.h>

#define DD    256
#define PLQ   65536           // plane elems (u16) = 256*256
#define SLOTB 131072          // complex slot elems (u16): re plane + im plane
#define NTS   128
#define DT_C  0.02f

typedef unsigned short u16;
typedef unsigned int   u32;
typedef __attribute__((ext_vector_type(8))) short s16x8;
typedef __attribute__((ext_vector_type(4))) float f32x4;

typedef __attribute__((address_space(1))) const unsigned int GU32;
typedef __attribute__((address_space(3))) unsigned int LU32;

// Plane = [64 rows][128B = 64 k-elems x 2B], XOR-swizzled. Involution.
__device__ __forceinline__ u32 swzB(u32 b) {
    return b ^ (((((b >> 7) ^ (b >> 10)) & 7u)) << 4);
}
__device__ __forceinline__ u16 f2bf(float f) {
    u32 u = __float_as_uint(f);
    return (u16)((u + 0x7FFFu + ((u >> 16) & 1u)) >> 16);
}
__device__ __forceinline__ float bf2f(u16 h) {
    return __uint_as_float(((u32)h) << 16);
}
__device__ __forceinline__ void gll16(const u16* g, char* ldsBase, u32 ldsByteOff) {
    u32 off = (u32)__builtin_amdgcn_readfirstlane((int)ldsByteOff);
    __builtin_amdgcn_global_load_lds((GU32*)g, (LU32*)(ldsBase + off), 16, 0, 0);
}

// ---------------------------------------------------------------------------
// build: X = DT * A_ts (bf16, N-layout only, float4 reads, no LDS).
// ---------------------------------------------------------------------------
__global__ __launch_bounds__(256)
void build_kernel(const float* __restrict__ cr, const float* __restrict__ ci,
                  const float* __restrict__ dre, const float* __restrict__ dimg,
                  const float* __restrict__ gre, const float* __restrict__ gim,
                  u16* __restrict__ Xn, int ts0)
{
    const int ts = blockIdx.y;
    const int k  = ts0 + ts;
    const int i4 = (blockIdx.x * 256 + threadIdx.x) * 4;   // 0..PLQ-4

    const float c0f = cr[2*k], c1f = cr[2*k+1];
    const float e0f = ci[2*k], e1f = ci[2*k+1];

    const float4 g0r = *(const float4*)&gre[0*PLQ + i4];
    const float4 g1r = *(const float4*)&gre[1*PLQ + i4];
    const float4 g2r = *(const float4*)&gre[2*PLQ + i4];
    const float4 g3r = *(const float4*)&gre[3*PLQ + i4];
    const float4 g0i = *(const float4*)&gim[0*PLQ + i4];
    const float4 g1i = *(const float4*)&gim[1*PLQ + i4];
    const float4 g2i = *(const float4*)&gim[2*PLQ + i4];
    const float4 g3i = *(const float4*)&gim[3*PLQ + i4];
    const float4 d_r = *(const float4*)&dre[i4];
    const float4 d_i = *(const float4*)&dimg[i4];
    const float* gr00 = &g0r.x; const float* gr01 = &g1r.x;
    const float* gr10 = &g2r.x; const float* gr11 = &g3r.x;
    const float* gi00 = &g0i.x; const float* gi01 = &g1i.x;
    const float* gi10 = &g2i.x; const float* gi11 = &g3i.x;
    const float* dr4  = &d_r.x; const float* di4  = &d_i.x;

    ushort4 hr, hi;
    u16* hrp = &hr.x; u16* hip = &hi.x;
    #pragma unroll
    for (int j = 0; j < 4; ++j) {
        const float are = dr4[j] + c0f*(gr00[j]+gr01[j]) + c1f*(gr10[j]+gr11[j])
                                 - e0f*(gi00[j]-gi01[j]) - e1f*(gi10[j]-gi11[j]);
        const float aim = di4[j] + c0f*(gi00[j]+gi01[j]) + c1f*(gi10[j]+gi11[j])
                                 + e0f*(gr00[j]-gr01[j]) + e1f*(gr10[j]-gr11[j]);
        hrp[j] = f2bf(DT_C * are);
        hip[j] = f2bf(DT_C * aim);
    }
    u16* X = Xn + (size_t)ts * SLOTB;
    *(ushort4*)&X[i4]       = hr;
    *(ushort4*)&X[PLQ + i4] = hi;
}

// ---------------------------------------------------------------------------
// Batched complex bf16 MFMA GEMM, 64x64 tile, 4 waves, BK=64, single 32 KB
// buffer. A: N-layout via gll16. B: N-layout [k][n], reg-prefetch + scatter
// (TRB=1; measured equal to the gll16 T-path, needs no transposed copy).
//   N-write: aN*acc + bN1*X1 + bN2*X2
// ---------------------------------------------------------------------------
template<int TRB>
__global__ __launch_bounds__(256)
void cgemm(const u16* __restrict__ Ab, const u16* __restrict__ Bb,
           u16* __restrict__ outN,
           const u16* __restrict__ X1b, const u16* __restrict__ X2b,
           float aN, float bN1, float bN2,
           int aS, int aO, int bS, int bO, int cS, int cO,
           int x1S, int x1O, int x2S, int x2O)
{
    __shared__ char lds[32768];

    // ---- bijective XCD-chunked block swizzle (nwg = 16*nz, always %8==0) ----
    const u32 nwg = 16u * (u32)gridDim.z;
    const u32 wg  = (u32)blockIdx.x + 4u*(u32)blockIdx.y + 16u*(u32)blockIdx.z;
    const u32 q   = nwg >> 3;
    const u32 w   = (wg & 7u) * q + (wg >> 3);
    const int bn = (int)(w & 3u) * 64;
    const int bm = (int)((w >> 2) & 3u) * 64;
    const int z  = (int)(w >> 4);

    const u16* __restrict__ A = Ab + (size_t)(z*aS + aO) * SLOTB;
    const u16* __restrict__ B = Bb + (size_t)(z*bS + bO) * SLOTB;

    const int t = threadIdx.x;

    // gll16 staging: plane-local dest byte b in {t*16, 4096+t*16};
    // source logical byte L = swzB(b) -> row = L>>7, k-elem = (L&127)>>1.
    const u32 b0 = (u32)t * 16u, b1 = 4096u + (u32)t * 16u;
    const u32 L0 = swzB(b0),     L1 = swzB(b1);
    const int rA0 = (int)(L0 >> 7), kA0 = (int)((L0 & 127u) >> 1);
    const int rA1 = (int)(L1 >> 7), kA1 = (int)((L1 & 127u) >> 1);
    const u32 wvoff = ((u32)(t >> 6)) * 1024u;

    const u16* pA0 = A + (size_t)(bm + rA0)*DD + kA0;
    const u16* pA1 = A + (size_t)(bm + rA1)*DD + kA1;

    // B scatter mapping (N-layout [k][n])
    const int kRow = t >> 3;                   // 0..31
    const int nCh  = t & 7;                    // n0 = nCh*8

    const int wv = t >> 6, ln = t & 63;
    const int wrow = (wv >> 1) * 32, wcol = (wv & 1) * 32;
    const int lg = ln >> 4, lc = ln & 15;

    f32x4 accR[2][2], accI[2][2];
    #pragma unroll
    for (int i = 0; i < 2; ++i)
        #pragma unroll
        for (int j = 0; j < 2; ++j) {
            accR[i][j] = (f32x4){0.f,0.f,0.f,0.f};
            accI[i][j] = (f32x4){0.f,0.f,0.f,0.f};
        }

    // ---- prologue: stage K-tile 0 ----
    {
        gll16(pA0,       lds, wvoff +     0u);
        gll16(pA1,       lds, wvoff +  4096u);
        gll16(pA0 + PLQ, lds, wvoff +  8192u);
        gll16(pA1 + PLQ, lds, wvoff + 12288u);
        #pragma unroll
        for (int h = 0; h < 2; ++h) {
            const int kk = h*32 + kRow;
            const s16x8 vr = *(const s16x8*)(B +       (size_t)kk*DD + bn + nCh*8);
            const s16x8 vi = *(const s16x8*)(B + PLQ + (size_t)kk*DD + bn + nCh*8);
            #pragma unroll
            for (int e = 0; e < 8; ++e) {
                const u32 off = swzB((u32)(nCh*8 + e)*128u + (u32)kk*2u);
                *(u16*)(lds + 16384 + off) = (u16)vr[e];
                *(u16*)(lds + 24576 + off) = (u16)vi[e];
            }
        }
    }
    __syncthreads();

    // ---- main loop: 4 K-phases ----
    for (int it = 0; it < 4; ++it) {
        s16x8 nvr0, nvi0, nvr1, nvi1;
        if (it < 3) {                          // prefetch next B tile to regs
            const int k1 = 64*(it + 1);
            nvr0 = *(const s16x8*)(B +       (size_t)(k1 + kRow)*DD + bn + nCh*8);
            nvi0 = *(const s16x8*)(B + PLQ + (size_t)(k1 + kRow)*DD + bn + nCh*8);
            nvr1 = *(const s16x8*)(B +       (size_t)(k1 + 32 + kRow)*DD + bn + nCh*8);
            nvi1 = *(const s16x8*)(B + PLQ + (size_t)(k1 + 32 + kRow)*DD + bn + nCh*8);
        }

        #pragma unroll
        for (int s = 0; s < 2; ++s) {          // two K=32 sub-steps
            s16x8 ar[2], ai[2], br[2], bi[2];
            #pragma unroll
            for (int fm = 0; fm < 2; ++fm) {
                const u32 so = swzB((u32)(wrow + fm*16 + lc)*128u + (u32)(s*4 + lg)*16u);
                ar[fm] = *(const s16x8*)(lds + so);
                ai[fm] = *(const s16x8*)(lds + 8192 + so);
            }
            #pragma unroll
            for (int fn = 0; fn < 2; ++fn) {
                const u32 so = swzB((u32)(wcol + fn*16 + lc)*128u + (u32)(s*4 + lg)*16u);
                br[fn] = *(const s16x8*)(lds + 16384 + so);
                bi[fn] = *(const s16x8*)(lds + 24576 + so);
            }
            #pragma unroll
            for (int fm = 0; fm < 2; ++fm)
                #pragma unroll
                for (int fn = 0; fn < 2; ++fn) {
                    accI[fm][fn] = __builtin_amdgcn_mfma_f32_16x16x32_bf16(ar[fm], bi[fn], accI[fm][fn], 0, 0, 0);
                    accI[fm][fn] = __builtin_amdgcn_mfma_f32_16x16x32_bf16(ai[fm], br[fn], accI[fm][fn], 0, 0, 0);
                }
            #pragma unroll
            for (int fm = 0; fm < 2; ++fm) ai[fm] ^= (short)0x8000u;
            #pragma unroll
            for (int fm = 0; fm < 2; ++fm)
                #pragma unroll
                for (int fn = 0; fn < 2; ++fn) {
                    accR[fm][fn] = __builtin_amdgcn_mfma_f32_16x16x32_bf16(ar[fm], br[fn], accR[fm][fn], 0, 0, 0);
                    accR[fm][fn] = __builtin_amdgcn_mfma_f32_16x16x32_bf16(ai[fm], bi[fn], accR[fm][fn], 0, 0, 0);
                }
        }

        if (it < 3) {
            const int k1 = 64*(it + 1);
            __syncthreads();                   // everyone done reading buffer
            gll16(pA0 + k1,       lds, wvoff +     0u);
            gll16(pA1 + k1,       lds, wvoff +  4096u);
            gll16(pA0 + PLQ + k1, lds, wvoff +  8192u);
            gll16(pA1 + PLQ + k1, lds, wvoff + 12288u);
            #pragma unroll
            for (int e = 0; e < 8; ++e) {
                const u32 off0 = swzB((u32)(nCh*8 + e)*128u + (u32)kRow*2u);
                const u32 off1 = swzB((u32)(nCh*8 + e)*128u + (u32)(32 + kRow)*2u);
                *(u16*)(lds + 16384 + off0) = (u16)nvr0[e];
                *(u16*)(lds + 24576 + off0) = (u16)nvi0[e];
                *(u16*)(lds + 16384 + off1) = (u16)nvr1[e];
                *(u16*)(lds + 24576 + off1) = (u16)nvi1[e];
            }
            __syncthreads();                   // buffer ready
        }
    }

    // ---- epilogue ----
    u16* oN = outN + (size_t)(z*cS + cO) * SLOTB;
    const u16* x1 = X1b ? X1b + (size_t)(z*x1S + x1O) * SLOTB : nullptr;
    const u16* x2 = X2b ? X2b + (size_t)(z*x2S + x2O) * SLOTB : nullptr;

    #pragma unroll
    for (int fm = 0; fm < 2; ++fm)
        #pragma unroll
        for (int fn = 0; fn < 2; ++fn) {
            const int rb = bm + wrow + fm*16 + lg*4;
            const int c  = bn + wcol + fn*16 + lc;
            #pragma unroll
            for (int j = 0; j < 4; ++j) {
                const int r = rb + j;
                float x1r = 0.f, x1i = 0.f, x2r = 0.f, x2i = 0.f;
                if (x1) { x1r = bf2f(x1[(size_t)r*DD + c]);
                          x1i = bf2f(x1[PLQ + (size_t)r*DD + c]); }
                if (x2) { x2r = bf2f(x2[(size_t)r*DD + c]);
                          x2i = bf2f(x2[PLQ + (size_t)r*DD + c]); }
                oN[(size_t)r*DD + c]       = f2bf(aN*accR[fm][fn][j] + bN1*x1r + bN2*x2r);
                oN[PLQ + (size_t)r*DD + c] = f2bf(aN*accI[fm][fn][j] + bN1*x1i + bN2*x2i);
            }
        }
}

// ---------------------------------------------------------------------------
// final: v = s0 + Etot@s0 ; c = sum(v[diag]) ; sT = v/c ; fid = ||sT-tgt||_F
// ---------------------------------------------------------------------------
__global__ __launch_bounds__(256)
void final_kernel(const u16* __restrict__ Et,
                  const float* __restrict__ s0r, const float* __restrict__ s0i,
                  const float* __restrict__ tgr, const float* __restrict__ tgi,
                  float* __restrict__ out, int outSize)
{
    __shared__ float sr[DD], si[DD], red[DD];
    __shared__ float cR, cI;
    const int t = threadIdx.x;
    sr[t] = s0r[t];
    si[t] = s0i[t];
    __syncthreads();

    const u16* Er = Et + (size_t)t*DD;
    const u16* Ei = Er + PLQ;
    float ar = sr[t], ai = si[t];
    for (int kk = 0; kk < DD/8; ++kk) {
        const s16x8 er = *(const s16x8*)(Er + kk*8);
        const s16x8 ei = *(const s16x8*)(Ei + kk*8);
        #pragma unroll
        for (int jj = 0; jj < 8; ++jj) {
            const float pr = bf2f((u16)er[jj]);
            const float pi = bf2f((u16)ei[jj]);
            const int k = kk*8 + jj;
            ar += pr*sr[k] - pi*si[k];
            ai += pr*si[k] + pi*sr[k];
        }
    }
    __syncthreads();
    sr[t] = ar; si[t] = ai;
    __syncthreads();

    if (t == 0) {
        float xr = 0.f, xi = 0.f;
        for (int i = 0; i < 16; ++i) { xr += sr[i*17]; xi += si[i*17]; }
        cR = xr; cI = xi;
    }
    __syncthreads();

    const float den = cR*cR + cI*cI;
    const float str = (ar*cR + ai*cI) / den;
    const float sti = (ai*cR - ar*cI) / den;

    const float dr = str - tgr[t];
    const float di = sti - tgi[t];
    red[t] = dr*dr + di*di;
    __syncthreads();
    for (int s = 128; s > 0; s >>= 1) {
        if (t < s) red[t] += red[t + s];
        __syncthreads();
    }
    const float fid = sqrtf(red[0]);

    if (outSize >= 2*DD + 1) {
        out[2*t] = str; out[2*t+1] = sti;
        if (t == 0) out[2*DD] = fid;
    } else if (outSize == 2*DD) {
        out[2*t] = str; out[2*t+1] = sti;
    } else {
        out[t] = str;
        if (t == 0 && outSize > DD) out[DD] = fid;
    }
}

// ---------------------------------------------------------------------------
extern "C" void kernel_launch(void* const* d_in, const int* in_sizes, int n_in,
                              void* d_out, int out_size, void* d_ws, size_t ws_size,
                              hipStream_t stream)
{
    (void)in_sizes; (void)n_in;
    const float* cr   = (const float*)d_in[0];
    const float* ci   = (const float*)d_in[1];
    const float* dre  = (const float*)d_in[2];
    const float* dimg = (const float*)d_in[3];
    const float* gre  = (const float*)d_in[4];
    const float* gim  = (const float*)d_in[5];
    const float* s0r  = (const float*)d_in[6];
    const float* s0i  = (const float*)d_in[7];
    const float* tgr  = (const float*)d_in[8];
    const float* tgi  = (const float*)d_in[9];

    // Degree-3 Taylor: E = X + P2/2 + (P2@X)/6, P2 = X@X.
    const float c2 = 0.5f, c3i = 1.f/6.f;

    u16* ws = (u16*)d_ws;
    const long slots = (long)(ws_size / 2) / SLOTB;

    if (slots >= 384) {
        // ============ FAST PATH: z=128, 3 regions, all-N layouts ============
        u16* RX = ws;                      // X (N)
        u16* R1 = ws + 128L * SLOTB;       // P2; tree odd levels
        u16* R2 = ws + 256L * SLOTB;       // E;  tree even levels

        build_kernel<<<dim3(PLQ/1024, 128), 256, 0, stream>>>(
            cr, ci, dre, dimg, gre, gim, RX, 0);

        const dim3 g128(4, 4, 128);
        // G1: P2 = X@X
        cgemm<1><<<g128, 256, 0, stream>>>(RX, RX, R1, nullptr, nullptr,
            1.f, 0.f, 0.f,
            1,0, 1,0, 1,0, 0,0, 0,0);
        // G2: E = (P2@X)/6 + X + P2/2 -> R2
        cgemm<1><<<g128, 256, 0, stream>>>(R1, RX, R2, RX, R1,
            c3i, 1.f, c2,
            1,0, 1,0, 1,0, 1,0, 1,0);

        // ---- tree: E' = Ea@Eb + Ea + Eb (all N-layout) ----
        u16* cur = R2;
        u16* oth = R1;
        for (int n = 128; n > 1; n >>= 1) {
            cgemm<1><<<dim3(4, 4, n/2), 256, 0, stream>>>(
                cur, cur, oth, cur, cur,
                1.f, 1.f, 1.f,
                2,1, 2,0, 1,0, 2,1, 2,0);
            u16* tmp = cur; cur = oth; oth = tmp;
        }
        final_kernel<<<1, 256, 0, stream>>>(cur, s0r, s0i, tgr, tgi,
                                            (float*)d_out, out_size);
    } else {
        // ============ FALLBACK: chunked (P + 2C regions) ====================
        u16* P  = ws;                      // final E, 128 slots
        u16* CB = ws + 128L * SLOTB;
        int C = (int)((slots - 128) / 2);
        if (C > NTS) C = NTS;
        if (C < 32)  C = 32;               // tree ping needs 2C >= 64

        for (int ts0 = 0; ts0 < NTS; ts0 += C) {
            int nb = NTS - ts0; if (nb > C) nb = C;
            u16* Xn = CB;
            u16* P2 = CB + 1L*C*SLOTB;

            build_kernel<<<dim3(PLQ/1024, nb), 256, 0, stream>>>(
                cr, ci, dre, dimg, gre, gim, Xn, ts0);

            const dim3 grid(4, 4, nb);
            cgemm<1><<<grid, 256, 0, stream>>>(Xn, Xn, P2, nullptr, nullptr,
                1.f, 0.f, 0.f,
                1,0, 1,0, 1,0, 0,0, 0,0);
            cgemm<1><<<grid, 256, 0, stream>>>(P2, Xn, P, Xn, P2,
                c3i, 1.f, c2,
                1,0, 1,0, 1,ts0, 1,0, 1,0);
        }

        u16* cur = P;
        u16* oth = CB;
        for (int n = 128; n > 1; n >>= 1) {
            cgemm<1><<<dim3(4, 4, n/2), 256, 0, stream>>>(
                cur, cur, oth, cur, cur,
                1.f, 1.f, 1.f,
                2,1, 2,0, 1,0, 2,1, 2,0);
            u16* tmp = cur; cur = oth; oth = tmp;
        }
        final_kernel<<<1, 256, 0, stream>>>(cur, s0r, s0i, tgr, tgi,
                                            (float*)d_out, out_size);
    }
}